// Round 7
// baseline (867.614 us; speedup 1.0000x reference)
//
#include <hip/hip_runtime.h>
#include <hip/hip_fp16.h>
#include <math.h>

#define SLOPE 0.2f

typedef short bf16x8 __attribute__((ext_vector_type(8)));
typedef float f32x4  __attribute__((ext_vector_type(4)));

static __device__ __forceinline__ float elu_f(float x){ return x > 0.f ? x : (__expf(x) - 1.f); }
static __device__ __forceinline__ float lrelu(float t){ return t > 0.f ? t : SLOPE*t; }
static __device__ __forceinline__ unsigned short f2bf_rne(float f){
    unsigned int u = __float_as_uint(f);
    unsigned int r = (u + 0x7FFFu + ((u >> 16) & 1u)) >> 16;
    return (unsigned short)r;
}
static __device__ __forceinline__ float bf2f(unsigned short h){ return __uint_as_float(((unsigned int)h) << 16); }

#define ASYNC_COPY16(gp, lp) \
    __builtin_amdgcn_global_load_lds((const __attribute__((address_space(1))) void*)(gp), \
                                     (__attribute__((address_space(3))) void*)(lp), 16, 0, 0)

// ---------------- CSR build (XCD-sliced by dst) ----------------
__global__ void __launch_bounds__(256) hist_sliced_kernel(const int* __restrict__ e0, int E, int n,
                                                          int* __restrict__ cnt){
    const int s = blockIdx.x & 7;
    const int c = blockIdx.x >> 3;
    const int K = gridDim.x >> 3;
    const int lo = (int)((long)s*n >> 3), hi = (int)((long)(s+1)*n >> 3);
    const int i0 = (int)((long)c*E/K), i1 = (int)((long)(c+1)*E/K);
    for (int i = i0 + threadIdx.x; i < i1; i += 256){
        int j = e0[i];
        if (j >= lo && j < hi) atomicAdd(&cnt[j], 1);
    }
}

// hierarchical exclusive scan over T cells: reduce -> small scan -> apply (in-place cnt->cursor)
__global__ void __launch_bounds__(256) scan_reduce_kernel(const int* __restrict__ cnt, int T, int* __restrict__ bsum){
    int c0 = blockIdx.x*4096 + threadIdx.x*16;
    int sum = 0;
    #pragma unroll
    for (int q = 0; q < 16; ++q){ int i = c0 + q; if (i < T) sum += cnt[i]; }
    #pragma unroll
    for (int off = 1; off < 64; off <<= 1) sum += __shfl_xor(sum, off, 64);
    __shared__ int ws_[4];
    int lane = threadIdx.x & 63, wid = threadIdx.x >> 6;
    if (lane == 0) ws_[wid] = sum;
    __syncthreads();
    if (threadIdx.x == 0) bsum[blockIdx.x] = ws_[0] + ws_[1] + ws_[2] + ws_[3];
}

__global__ void __launch_bounds__(512) scan_small_kernel(const int* __restrict__ bsum, int NB, int* __restrict__ bexcl){
    int t = threadIdx.x;
    int v = (t < NB) ? bsum[t] : 0;
    int lane = t & 63, wid = t >> 6;
    int val = v;
    #pragma unroll
    for (int off = 1; off < 64; off <<= 1){ int u = __shfl_up(val, off, 64); if (lane >= off) val += u; }
    __shared__ int wt[8];
    if (lane == 63) wt[wid] = val;
    __syncthreads();
    int base = 0;
    for (int w2 = 0; w2 < wid; ++w2) base += wt[w2];
    if (t < NB) bexcl[t] = base + val - v;
}

__global__ void __launch_bounds__(256) scan_apply_kernel(int* __restrict__ cnt_cur, int T,
                                                         const int* __restrict__ bexcl){
    int c0 = blockIdx.x*4096 + threadIdx.x*16;
    int v[16];
    #pragma unroll
    for (int q = 0; q < 16; ++q){ int i = c0 + q; v[q] = (i < T) ? cnt_cur[i] : 0; }
    int tsum = 0;
    #pragma unroll
    for (int q = 0; q < 16; ++q){ int t_ = v[q]; v[q] = tsum; tsum += t_; }
    int lane = threadIdx.x & 63, wid = threadIdx.x >> 6;
    int val = tsum;
    #pragma unroll
    for (int off = 1; off < 64; off <<= 1){ int u = __shfl_up(val, off, 64); if (lane >= off) val += u; }
    __shared__ int wt[4];
    if (lane == 63) wt[wid] = val;
    __syncthreads();
    int base = bexcl[blockIdx.x];
    for (int w2 = 0; w2 < wid; ++w2) base += wt[w2];
    base += val - tsum;
    #pragma unroll
    for (int q = 0; q < 16; ++q){ int i = c0 + q; if (i < T) cnt_cur[i] = base + v[q]; }
}

// scatter + per-edge 8-head weight precompute: w[h] = exp(lrelu(ssrc[dst,h]+sdst[src,h])) as bf16
__global__ void __launch_bounds__(256) scatter_w_kernel(const int* __restrict__ e0, const int* __restrict__ e1,
                                                        int E, int n,
                                                        const float* __restrict__ ssrc1, const float* __restrict__ sdst1,
                                                        int* __restrict__ cursor, int* __restrict__ sidx,
                                                        uint4* __restrict__ wgt8){
    const int s = blockIdx.x & 7;
    const int c = blockIdx.x >> 3;
    const int K = gridDim.x >> 3;
    const int lo = (int)((long)s*n >> 3), hi = (int)((long)(s+1)*n >> 3);
    const int i0 = (int)((long)c*E/K), i1 = (int)((long)(c+1)*E/K);
    for (int i = i0 + threadIdx.x; i < i1; i += 256){
        int j = e0[i];
        if (j >= lo && j < hi){
            int jj = e1[i];
            int p = atomicAdd(&cursor[j], 1);
            sidx[p] = jj;
            float4 sa0 = *(const float4*)(ssrc1 + (size_t)j*8);
            float4 sa1 = *(const float4*)(ssrc1 + (size_t)j*8 + 4);
            float4 sb0 = *(const float4*)(sdst1 + (size_t)jj*8);
            float4 sb1 = *(const float4*)(sdst1 + (size_t)jj*8 + 4);
            float w_[8];
            w_[0] = __expf(lrelu(sa0.x + sb0.x));
            w_[1] = __expf(lrelu(sa0.y + sb0.y));
            w_[2] = __expf(lrelu(sa0.z + sb0.z));
            w_[3] = __expf(lrelu(sa0.w + sb0.w));
            w_[4] = __expf(lrelu(sa1.x + sb1.x));
            w_[5] = __expf(lrelu(sa1.y + sb1.y));
            w_[6] = __expf(lrelu(sa1.z + sb1.z));
            w_[7] = __expf(lrelu(sa1.w + sb1.w));
            uint4 pk;
            pk.x = (unsigned)f2bf_rne(w_[0]) | ((unsigned)f2bf_rne(w_[1]) << 16);
            pk.y = (unsigned)f2bf_rne(w_[2]) | ((unsigned)f2bf_rne(w_[3]) << 16);
            pk.z = (unsigned)f2bf_rne(w_[4]) | ((unsigned)f2bf_rne(w_[5]) << 16);
            pk.w = (unsigned)f2bf_rne(w_[6]) | ((unsigned)f2bf_rne(w_[7]) << 16);
            wgt8[p] = pk;
        }
    }
}

// ---------------- prep: split x into bf16 hi/lo ----------------
__global__ void __launch_bounds__(256) split_x_kernel(const float* __restrict__ x,
                                                      unsigned short* __restrict__ xhi,
                                                      unsigned short* __restrict__ xlo, int total4){
    int i = blockIdx.x*256 + threadIdx.x;
    if (i >= total4) return;
    float4 v = ((const float4*)x)[i];
    ushort4 h, l;
    h.x = f2bf_rne(v.x); l.x = f2bf_rne(v.x - bf2f(h.x));
    h.y = f2bf_rne(v.y); l.y = f2bf_rne(v.y - bf2f(h.y));
    h.z = f2bf_rne(v.z); l.z = f2bf_rne(v.z - bf2f(h.z));
    h.w = f2bf_rne(v.w); l.w = f2bf_rne(v.w - bf2f(h.w));
    ((ushort4*)xhi)[i] = h;
    ((ushort4*)xlo)[i] = l;
}

// ---------------- prep: W1 [8][512][64] -> wT [512 cols][512 k] bf16 hi/lo (col = head*64+f) ----------------
__global__ void __launch_bounds__(256) prep_w_kernel(const float* __restrict__ W1,
                                                     unsigned short* __restrict__ wThi,
                                                     unsigned short* __restrict__ wTlo){
    int idx = blockIdx.x*256 + threadIdx.x;          // 8*64*512 = 262144
    int head = idx >> 15, rem = idx & 32767;
    int c = rem >> 9, k = rem & 511;
    float f = W1[((size_t)head << 15) + k*64 + c];
    unsigned short h = f2bf_rne(f);
    wThi[idx] = h;
    wTlo[idx] = f2bf_rne(f - bf2f(h));
}

// ---------------- layer 1: LDS-staged split-bf16 MFMA GEMM + fused scores ----------------
__global__ void __launch_bounds__(256) gemm1_mfma_kernel(const unsigned short* __restrict__ xhi,
                                                         const unsigned short* __restrict__ xlo,
                                                         const unsigned short* __restrict__ wThi,
                                                         const unsigned short* __restrict__ wTlo,
                                                         const float* __restrict__ a1,
                                                         __half* __restrict__ h_g,
                                                         float* __restrict__ ssrc, float* __restrict__ sdst,
                                                         int n, int nwg){
    __shared__ unsigned short lds[16384];   // 32 KB: Ahi | Alo | Bhi | Blo, each [128][32] bf16
    const int bid = blockIdx.x;
    const int xcd = bid & 7, jj = bid >> 3;
    const int q = nwg >> 3, r = nwg & 7;
    const int logical = (xcd < r ? xcd*(q+1) : r*(q+1) + (xcd-r)*q) + jj;
    const int rowtile = logical >> 2, ct = logical & 3;
    const int row0 = rowtile*128, col0 = ct*128;
    const int w = threadIdx.x >> 6, lane = threadIdx.x & 63;
    const int wm = w >> 1, wn = w & 1;
    const int lr = lane & 15, lk = lane >> 4;
    f32x4 acc[4][4] = {};
    const unsigned short* sbase[8];
    unsigned int soff[8];
    #pragma unroll
    for (int i = 0; i < 8; ++i){
        unsigned int off = w*8192u + i*1024u + lane*16u;
        unsigned int arr = off >> 13, within = off & 8191u;
        unsigned int rrow = within >> 6, kel = (within & 63u) >> 1;
        const unsigned short* g;
        size_t gidx;
        if (arr == 0)      { g = xhi;  gidx = (size_t)(row0 + rrow)*512 + kel; }
        else if (arr == 1) { g = xlo;  gidx = (size_t)(row0 + rrow)*512 + kel; }
        else if (arr == 2) { g = wThi; gidx = (size_t)(col0 + rrow)*512 + kel; }
        else               { g = wTlo; gidx = (size_t)(col0 + rrow)*512 + kel; }
        sbase[i] = g + gidx;
        soff[i] = (w*8192u + i*1024u);
    }
    const unsigned short* Ahi = lds;
    const unsigned short* Alo = lds + 4096;
    const unsigned short* Bhi = lds + 8192;
    const unsigned short* Blo = lds + 12288;
    for (int k0 = 0; k0 < 512; k0 += 32){
        #pragma unroll
        for (int i = 0; i < 8; ++i)
            ASYNC_COPY16(sbase[i] + k0, (char*)lds + soff[i]);
        __syncthreads();
        bf16x8 a_h[4], a_l[4], b_h[4], b_l[4];
        #pragma unroll
        for (int mi = 0; mi < 4; ++mi){
            int rowl = wm*64 + mi*16 + lr;
            a_h[mi] = *(const bf16x8*)(Ahi + rowl*32 + lk*8);
            a_l[mi] = *(const bf16x8*)(Alo + rowl*32 + lk*8);
        }
        #pragma unroll
        for (int ni = 0; ni < 4; ++ni){
            int coll = wn*64 + ni*16 + lr;
            b_h[ni] = *(const bf16x8*)(Bhi + coll*32 + lk*8);
            b_l[ni] = *(const bf16x8*)(Blo + coll*32 + lk*8);
        }
        #pragma unroll
        for (int mi = 0; mi < 4; ++mi)
            #pragma unroll
            for (int ni = 0; ni < 4; ++ni){
                f32x4& A = acc[mi][ni];
                A = __builtin_amdgcn_mfma_f32_16x16x32_bf16(a_h[mi], b_h[ni], A, 0, 0, 0);
                A = __builtin_amdgcn_mfma_f32_16x16x32_bf16(a_h[mi], b_l[ni], A, 0, 0, 0);
                A = __builtin_amdgcn_mfma_f32_16x16x32_bf16(a_l[mi], b_h[ni], A, 0, 0, 0);
            }
        __syncthreads();
    }
    const int head = ct*2 + wn;
    float as_[4], ad_[4];
    #pragma unroll
    for (int ni = 0; ni < 4; ++ni){
        as_[ni] = a1[(size_t)head*128 + ni*16 + lr];
        ad_[ni] = a1[(size_t)head*128 + 64 + ni*16 + lr];
    }
    #pragma unroll
    for (int mi = 0; mi < 4; ++mi){
        #pragma unroll
        for (int reg = 0; reg < 4; ++reg){
            float s = 0.f, d = 0.f;
            #pragma unroll
            for (int ni = 0; ni < 4; ++ni){
                float v = acc[mi][ni][reg];
                s += v*as_[ni]; d += v*ad_[ni];
            }
            s += __shfl_xor(s, 1); d += __shfl_xor(d, 1);
            s += __shfl_xor(s, 2); d += __shfl_xor(d, 2);
            s += __shfl_xor(s, 4); d += __shfl_xor(d, 4);
            s += __shfl_xor(s, 8); d += __shfl_xor(d, 8);
            const int node = row0 + wm*64 + mi*16 + lk*4 + reg;
            if (node < n){
                #pragma unroll
                for (int ni = 0; ni < 4; ++ni)
                    h_g[(size_t)node*512 + head*64 + ni*16 + lr] = __float2half(acc[mi][ni][reg]);
                if (lr == 0){
                    ssrc[(size_t)node*8 + head] = s;
                    sdst[(size_t)node*8 + head] = d;
                }
            }
        }
    }
}

// ---------------- layer 1 aggregation: one wave per node, 8 heads; precomputed bf16 weights, 8-deep MLP ----------------
__global__ void __launch_bounds__(256) agg1_kernel(const __half* __restrict__ h_g,
                                                   const unsigned short* __restrict__ wgt,   // [E][8] bf16
                                                   const int* __restrict__ bend, const int* __restrict__ sidx,
                                                   __half* __restrict__ hcat, int n){
    const int w = threadIdx.x >> 6, lane = threadIdx.x & 63;
    const int node = blockIdx.x*4 + w;
    if (node >= n) return;
    const int r0 = node ? bend[node-1] : 0;
    const int r1 = bend[node];
    const int h = lane >> 3;
    float acc[8] = {};
    float wsum = 0.f;
    int e = r0;
    for (; e + 7 < r1; e += 8){
        int j[8];
        #pragma unroll
        for (int qq = 0; qq < 8; ++qq) j[qq] = sidx[e+qq];
        uint4 g[8];
        #pragma unroll
        for (int qq = 0; qq < 8; ++qq) g[qq] = *(const uint4*)(h_g + (size_t)j[qq]*512 + lane*8);
        float wv[8];
        #pragma unroll
        for (int qq = 0; qq < 8; ++qq) wv[qq] = bf2f(wgt[(size_t)(e+qq)*8 + h]);
        #pragma unroll
        for (int qq = 0; qq < 8; ++qq){
            const unsigned int* u = &g[qq].x;
            float wq = wv[qq];
            #pragma unroll
            for (int p2 = 0; p2 < 4; ++p2){
                float2 f = __half22float2(*(const __half2*)&u[p2]);
                acc[2*p2]   += wq*f.x;
                acc[2*p2+1] += wq*f.y;
            }
            wsum += wq;
        }
    }
    for (; e < r1; ++e){
        int j = sidx[e];
        uint4 g = *(const uint4*)(h_g + (size_t)j*512 + lane*8);
        float wq = bf2f(wgt[(size_t)e*8 + h]);
        const unsigned int* u = &g.x;
        #pragma unroll
        for (int p2 = 0; p2 < 4; ++p2){
            float2 f = __half22float2(*(const __half2*)&u[p2]);
            acc[2*p2]   += wq*f.x;
            acc[2*p2+1] += wq*f.y;
        }
        wsum += wq;
    }
    float inv = 1.f / wsum;
    union { uint4 u; __half hv[8]; } pk;
    #pragma unroll
    for (int qq = 0; qq < 8; ++qq) pk.hv[qq] = __float2half(elu_f(acc[qq]*inv));
    *(uint4*)(hcat + (size_t)node*512 + lane*8) = pk.u;
}

// ---------------- layer 2 GEMM (+ scores fused): hcat(fp16)[n,512] @ W2[512,20] ----------------
__global__ void __launch_bounds__(256) gemm2_kernel(const __half* __restrict__ hcat, const float* __restrict__ W2,
                                                    const float* __restrict__ a2,
                                                    float* __restrict__ h2, float* __restrict__ ssrc,
                                                    float* __restrict__ sdst, int n){
    __shared__ float As[16][257];
    __shared__ float Ws[16][20];
    const int tid = threadIdx.x;
    const int node = blockIdx.x*256 + tid;
    float acc[20] = {};
    for (int k0 = 0; k0 < 512; k0 += 16){
        uint4 u0 = {0,0,0,0}, u1 = {0,0,0,0};
        if (node < n){
            const __half* src = hcat + (size_t)node*512 + k0;
            u0 = *(const uint4*)src;
            u1 = *(const uint4*)(src + 8);
        }
        const unsigned int* ua = &u0.x;
        const unsigned int* ub = &u1.x;
        #pragma unroll
        for (int qq = 0; qq < 4; ++qq){
            float2 f = __half22float2(*(const __half2*)&ua[qq]);
            As[2*qq][tid] = f.x; As[2*qq+1][tid] = f.y;
            float2 g = __half22float2(*(const __half2*)&ub[qq]);
            As[8+2*qq][tid] = g.x; As[8+2*qq+1][tid] = g.y;
        }
        for (int qq = tid; qq < 320; qq += 256){
            int kr = qq/20, cc = qq%20;
            Ws[kr][cc] = W2[(size_t)(k0 + kr)*20 + cc];
        }
        __syncthreads();
        #pragma unroll
        for (int kk = 0; kk < 16; ++kk){
            float a = As[kk][tid];
            #pragma unroll
            for (int cc = 0; cc < 20; ++cc) acc[cc] += a*Ws[kk][cc];
        }
        __syncthreads();
    }
    if (node < n){
        float s0 = 0.f, s1 = 0.f;
        #pragma unroll
        for (int cc = 0; cc < 20; ++cc){
            h2[(size_t)node*20 + cc] = acc[cc];
            s0 += acc[cc]*a2[cc];
            s1 += acc[cc]*a2[20 + cc];
        }
        ssrc[node] = s0; sdst[node] = s1;
    }
}

// ---------------- layer 2 aggregation: 8-deep MLP ----------------
__global__ void __launch_bounds__(256) agg2_kernel(const float* __restrict__ h2, const float* __restrict__ ssrc,
                                                   const float* __restrict__ sdstv,
                                                   const int* __restrict__ bend, const int* __restrict__ sidx,
                                                   float* __restrict__ out, int n){
    const int w = threadIdx.x >> 6, lane = threadIdx.x & 63;
    const int node = blockIdx.x*4 + w;
    if (node >= n) return;
    const int r0 = node ? bend[node-1] : 0;
    const int r1 = bend[node];
    const float ss = ssrc[node];
    const bool act = lane < 20;
    float acc = 0.f, wsum = 0.f;
    int e = r0;
    for (; e + 7 < r1; e += 8){
        int j[8];
        #pragma unroll
        for (int qq = 0; qq < 8; ++qq) j[qq] = sidx[e+qq];
        float v[8], s[8];
        #pragma unroll
        for (int qq = 0; qq < 8; ++qq) v[qq] = act ? h2[(size_t)j[qq]*20 + lane] : 0.f;
        #pragma unroll
        for (int qq = 0; qq < 8; ++qq) s[qq] = sdstv[j[qq]];
        #pragma unroll
        for (int qq = 0; qq < 8; ++qq){
            float wq = __expf(lrelu(ss + s[qq]));
            acc += wq*v[qq];
            wsum += wq;
        }
    }
    for (; e < r1; ++e){
        int j = sidx[e];
        float v = act ? h2[(size_t)j*20 + lane] : 0.f;
        float wq = __expf(lrelu(ss + sdstv[j]));
        acc += wq*v; wsum += wq;
    }
    if (act) out[(size_t)node*20 + lane] = elu_f(acc / wsum);
}

extern "C" void kernel_launch(void* const* d_in, const int* in_sizes, int n_in,
                              void* d_out, int out_size, void* d_ws, size_t ws_size,
                              hipStream_t stream){
    const float* x  = (const float*)d_in[0];
    const float* W1 = (const float*)d_in[1];
    const float* a1 = (const float*)d_in[2];
    const float* W2 = (const float*)d_in[3];
    const float* a2 = (const float*)d_in[4];
    const int*   ei = (const int*)d_in[5];
    const int n = in_sizes[0] / 512;
    const int E = in_sizes[5] / 2;
    const int* e0 = ei;
    const int* e1 = ei + E;

    char* p = (char*)d_ws;
    auto alloc = [&](size_t bytes)->char*{ char* r = p; p += (bytes + 255) & ~(size_t)255; return r; };
    unsigned short* xhi  = (unsigned short*)alloc((size_t)n*512*2);   // 51.2 MB (-> hcat after gemm1)
    unsigned short* xlo  = (unsigned short*)alloc((size_t)n*512*2);   // 51.2 MB (-> h2 + CSR after gemm1)
    __half*         h_g  = (__half*)        alloc((size_t)n*512*2);   // 51.2 MB
    unsigned short* wThi = (unsigned short*)alloc((size_t)8*64*512*2);
    unsigned short* wTlo = (unsigned short*)alloc((size_t)8*64*512*2);
    float* ssrc1   = (float*)alloc((size_t)n*8*4);
    float* sdst1   = (float*)alloc((size_t)n*8*4);
    // aliases inside xhi/xlo (both dead after gemm1):
    __half* hcat  = (__half*)xhi;                        // agg1 output
    // bump allocator over the xlo region for phase-2/3 buffers:
    char* q2 = (char*)xlo;
    auto alloc2 = [&](size_t bytes)->char*{ char* r = q2; q2 += (bytes + 255) & ~(size_t)255; return r; };
    float* h2    = (float*)alloc2((size_t)n*20*4);       // 4.0 MB
    float* ssrc2 = (float*)alloc2((size_t)n*4);
    float* sdst2 = (float*)alloc2((size_t)n*4);
    int*   cursor = (int*)  alloc2((size_t)n*4);         // cnt -> prefix -> bucket ends
    int*   sidx   = (int*)  alloc2((size_t)E*4);         // 6.6 MB
    int*   bsum   = (int*)  alloc2(4096);
    int*   bexcl  = (int*)  alloc2(4096);
    uint4* wgt8   = (uint4*)alloc2((size_t)E*16);        // 26.4 MB (bf16 x 8 heads per edge)

    // ---- phase 1: dense layer-1 GEMM ----
    const int total4 = n*512/4;
    split_x_kernel<<<(total4 + 255)/256, 256, 0, stream>>>(x, xhi, xlo, total4);
    prep_w_kernel <<<1024, 256, 0, stream>>>(W1, wThi, wTlo);
    const int mb = (n + 127)/128;
    const int nwg = mb*4;
    gemm1_mfma_kernel<<<nwg, 256, 0, stream>>>(xhi, xlo, wThi, wTlo, a1, h_g, ssrc1, sdst1, n, nwg);

    // ---- phase 2: CSR build + per-edge weight precompute ----
    hipMemsetAsync(cursor, 0, (size_t)n*4, stream);
    const int KCH = 192;
    hist_sliced_kernel<<<KCH*8, 256, 0, stream>>>(e0, E, n, cursor);
    const int NB = (n + 4095)/4096;
    scan_reduce_kernel<<<NB, 256, 0, stream>>>(cursor, n, bsum);
    scan_small_kernel <<<1, 512, 0, stream>>>(bsum, NB, bexcl);
    scan_apply_kernel <<<NB, 256, 0, stream>>>(cursor, n, bexcl);
    scatter_w_kernel  <<<KCH*8, 256, 0, stream>>>(e0, e1, E, n, ssrc1, sdst1, cursor, sidx, wgt8);
    // after scatter, cursor[node] = end of node's edge range

    // ---- phase 3: aggregation + layer 2 ----
    agg1_kernel<<<(n + 3)/4, 256, 0, stream>>>(h_g, (const unsigned short*)wgt8, cursor, sidx, hcat, n);
    const int nb256 = (n + 255)/256;
    gemm2_kernel<<<nb256, 256, 0, stream>>>(hcat, W2, a2, h2, ssrc2, sdst2, n);
    agg2_kernel <<<(n + 3)/4, 256, 0, stream>>>(h2, ssrc2, sdst2, cursor, sidx, (float*)d_out, n);
}